// Round 1
// 277.583 us; speedup vs baseline: 1.0278x; 1.0278x over previous
//
#include <hip/hip_runtime.h>

// MHA forward, bf16 MFMA everywhere. B=4 S=2048 H=1024 NH=16 D=64.
// R8: attn P-transpose moved from LDS (bank-conflicted Ps, stride-40) to
// in-register cvt_pk + v_permlane16_swap_b32 (T12-style). The swap pair
// produces an A-fragment with k-chunk->quad mapping sigma=(0,2,1,3); the V
// B-fragment LDS read is chunk-permuted identically so the MFMA contraction
// stays aligned. Ps eliminated (LDS 53248 -> 32768B). qkv/proj_out unchanged.

#define DEV __device__ __forceinline__

typedef __bf16 bf16x8 __attribute__((ext_vector_type(8)));
typedef __bf16 bf16x4 __attribute__((ext_vector_type(4)));
typedef __bf16 bf16x2 __attribute__((ext_vector_type(2)));
typedef float floatx4 __attribute__((ext_vector_type(4)));
typedef unsigned int uintx4 __attribute__((ext_vector_type(4)));

constexpr int Bdim = 4, SS = 2048, HH = 1024, NHH = 16, DD = 64;
constexpr int MM = Bdim * SS;  // 8192

DEV void async16(const void* g, void* l) {
  __builtin_amdgcn_global_load_lds(
      (const __attribute__((address_space(1))) unsigned int*)g,
      (__attribute__((address_space(3))) unsigned int*)l, 16, 0, 0);
}

DEV int swz2(int r) { return (r ^ (r >> 2)) & 3; }   // 4-chunk rows (BK=32)
DEV int swz3(int r) { return (r ^ (r >> 3)) & 7; }   // 8-chunk rows (64 cols)

// pack two f32 -> one dword of 2 bf16 (compiler emits v_cvt_pk_bf16_f32)
DEV unsigned pkbf16(float lo, float hi) {
  bf16x2 t;
  t[0] = (__bf16)lo;
  t[1] = (__bf16)hi;
  return __builtin_bit_cast(unsigned, t);
}

// v_permlane16_swap_b32: a.row{1,3} <-> b.row{0,2} (rows = 16-lane groups).
// After: a = [a0,b0,a2,b2], b = [a1,b1,a3,b3].
DEV void pswap16(unsigned& a, unsigned& b) {
  asm("v_permlane16_swap_b32 %0, %1" : "+v"(a), "+v"(b));
}

// ---------------- cast fp32 -> bf16 ----------------
__global__ __launch_bounds__(256) void cast_bf16_kernel(
    const float* __restrict__ x, const float* __restrict__ wq,
    const float* __restrict__ wk, const float* __restrict__ wv,
    const float* __restrict__ wo,
    __bf16* __restrict__ xb, __bf16* __restrict__ wqb, __bf16* __restrict__ wkb,
    __bf16* __restrict__ wvb, __bf16* __restrict__ wob) {
  const float* src; __bf16* dst; int n4;
  switch (blockIdx.z) {
    case 0: src = x;  dst = xb;  n4 = MM * HH / 4; break;
    case 1: src = wq; dst = wqb; n4 = HH * HH / 4; break;
    case 2: src = wk; dst = wkb; n4 = HH * HH / 4; break;
    case 3: src = wv; dst = wvb; n4 = HH * HH / 4; break;
    default: src = wo; dst = wob; n4 = HH * HH / 4; break;
  }
  int stride = gridDim.x * blockDim.x;
  for (int i = blockIdx.x * blockDim.x + threadIdx.x; i < n4; i += stride) {
    float4 v = ((const float4*)src)[i];
    bf16x4 o;
    o[0] = (__bf16)v.x; o[1] = (__bf16)v.y; o[2] = (__bf16)v.z; o[3] = (__bf16)v.w;
    ((bf16x4*)dst)[i] = o;
  }
}

// ---------------- mode-fused QKV projection (R6) ----------------
__global__ __launch_bounds__(256, 3) void proj_qkv_kernel(
    const __bf16* __restrict__ xb,
    const __bf16* __restrict__ wqb, const __bf16* __restrict__ wkb,
    const __bf16* __restrict__ wvb,
    const float* __restrict__ bq, const float* __restrict__ bk,
    const float* __restrict__ bv,
    __bf16* __restrict__ Q, __bf16* __restrict__ Kc, __bf16* __restrict__ Vt) {
  __shared__ __align__(16) __bf16 As[2][128 * 32];
  __shared__ __align__(16) __bf16 Bs[2][3][64 * 32];

  const int lid = blockIdx.x;
  const int xcd = lid & 7, slot = lid >> 3;
  const int mp = xcd + 8 * (slot >> 4);  // 0..63 : same-m -> same XCD
  const int np = slot & 15;              // 0..15
  const int m0 = mp * 128, n0 = np * 64;

  const int t = threadIdx.x;
  const int lane = t & 63, quad = lane >> 4, l16 = lane & 15;
  const int wid = t >> 6;

  const __bf16* const Wm[3] = {wqb, wkb, wvb};

  const int srow = t >> 2, sc = t & 3;
  const __bf16* Ag0 = xb + (size_t)(m0 + srow) * HH + (sc ^ swz2(srow)) * 8;
  const __bf16* Ag1 = xb + (size_t)(m0 + srow + 64) * HH + (sc ^ swz2(srow + 64)) * 8;
  const __bf16* Bg[3];
#pragma unroll
  for (int mo = 0; mo < 3; ++mo)
    Bg[mo] = Wm[mo] + (size_t)(n0 + srow) * HH + (sc ^ swz2(srow)) * 8;

  int aoff[2], boff[4];
#pragma unroll
  for (int mi = 0; mi < 2; ++mi) {
    int ra = wid * 32 + mi * 16 + l16;
    aoff[mi] = ra * 32 + (quad ^ swz2(ra)) * 8;
  }
#pragma unroll
  for (int ni = 0; ni < 4; ++ni) {
    int rb = ni * 16 + l16;
    boff[ni] = rb * 32 + (quad ^ swz2(rb)) * 8;
  }

  floatx4 acc[3][2][4] = {};

  async16(Ag0, &As[0][t * 8]);
  async16(Ag1, &As[0][2048 + t * 8]);
#pragma unroll
  for (int mo = 0; mo < 3; ++mo) async16(Bg[mo], &Bs[0][mo][t * 8]);

  for (int it = 0; it < HH / 32; ++it) {
    const int cur = it & 1;
    __syncthreads();

    if (it + 1 < HH / 32) {
      const int k = (it + 1) * 32;
      const int nxt = cur ^ 1;
      async16(Ag0 + k, &As[nxt][t * 8]);
      async16(Ag1 + k, &As[nxt][2048 + t * 8]);
#pragma unroll
      for (int mo = 0; mo < 3; ++mo) async16(Bg[mo] + k, &Bs[nxt][mo][t * 8]);
    }

    bf16x8 af[2];
#pragma unroll
    for (int mi = 0; mi < 2; ++mi) af[mi] = *(const bf16x8*)&As[cur][aoff[mi]];
#pragma unroll
    for (int mo = 0; mo < 3; ++mo) {
      bf16x8 bfr[4];
#pragma unroll
      for (int ni = 0; ni < 4; ++ni) bfr[ni] = *(const bf16x8*)&Bs[cur][mo][boff[ni]];
#pragma unroll
      for (int mi = 0; mi < 2; ++mi)
#pragma unroll
        for (int ni = 0; ni < 4; ++ni)
          acc[mo][mi][ni] = __builtin_amdgcn_mfma_f32_16x16x32_bf16(
              af[mi], bfr[ni], acc[mo][mi][ni], 0, 0, 0);
    }
  }

  const float qscale = 0.125f * 1.44269504088896f;  // 1/sqrt(D) * log2(e)
#pragma unroll
  for (int mo = 0; mo < 3; ++mo) {
    const float* bias = mo == 0 ? bq : mo == 1 ? bk : bv;
#pragma unroll
    for (int ni = 0; ni < 4; ++ni) {
      int n = n0 + ni * 16 + l16;
      float bval = bias[n];
      int h = n >> 6, d = n & 63;
#pragma unroll
      for (int mi = 0; mi < 2; ++mi) {
        int mbase = m0 + wid * 32 + mi * 16 + quad * 4;
        int bb = mbase >> 11, sbase = mbase & (SS - 1);
        size_t bh = (size_t)(bb * NHH + h);
        if (mo == 2) {
          bf16x4 pv;
#pragma unroll
          for (int r = 0; r < 4; ++r) pv[r] = (__bf16)(acc[mo][mi][ni][r] + bval);
          *(bf16x4*)&Vt[(bh * DD + d) * SS + sbase] = pv;
        } else {
#pragma unroll
          for (int r = 0; r < 4; ++r) {
            float v = acc[mo][mi][ni][r] + bval;
            if (mo == 0) Q [(bh * SS + sbase + r) * DD + d] = (__bf16)(v * qscale);
            else         Kc[(bh * SS + sbase + r) * DD + d] = (__bf16)v;
          }
        }
      }
    }
  }
}

// ------- 128x128 GEMM core, double-buffered, 1 barrier/K-chunk (R5) -------
DEV void gemm_db128(const __bf16* __restrict__ Ablk, const __bf16* __restrict__ Bblk,
                    __bf16* As, __bf16* Bs, floatx4 acc[4][4]) {
  const int t = threadIdx.x;
  const int lane = t & 63, quad = lane >> 4, l16 = lane & 15;
  const int wid = t >> 6;
  const int wm = (wid >> 1) * 64, wn = (wid & 1) * 64;

  const int srow = t >> 2, sc = t & 3;
  const __bf16* Ag0 = Ablk + (size_t)srow * HH + (sc ^ swz2(srow)) * 8;
  const __bf16* Ag1 = Ablk + (size_t)(srow + 64) * HH + (sc ^ swz2(srow + 64)) * 8;
  const __bf16* Bg0 = Bblk + (size_t)srow * HH + (sc ^ swz2(srow)) * 8;
  const __bf16* Bg1 = Bblk + (size_t)(srow + 64) * HH + (sc ^ swz2(srow + 64)) * 8;

  int aoff[4], boff[4];
#pragma unroll
  for (int i = 0; i < 4; ++i) {
    int ra = wm + i * 16 + l16;
    aoff[i] = ra * 32 + (quad ^ swz2(ra)) * 8;
    int rb = wn + i * 16 + l16;
    boff[i] = rb * 32 + (quad ^ swz2(rb)) * 8;
  }

  async16(Ag0, As + t * 8);
  async16(Ag1, As + 2048 + t * 8);
  async16(Bg0, Bs + t * 8);
  async16(Bg1, Bs + 2048 + t * 8);

  for (int it = 0; it < HH / 32; ++it) {
    const int cur = it & 1;
    __syncthreads();

    if (it + 1 < HH / 32) {
      const int k = (it + 1) * 32;
      const int nxt = (cur ^ 1) * 4096;
      async16(Ag0 + k, As + nxt + t * 8);
      async16(Ag1 + k, As + nxt + 2048 + t * 8);
      async16(Bg0 + k, Bs + nxt + t * 8);
      async16(Bg1 + k, Bs + nxt + 2048 + t * 8);
    }

    bf16x8 af[4], bfr[4];
#pragma unroll
    for (int i = 0; i < 4; ++i) {
      af[i]  = *(const bf16x8*)&As[cur * 4096 + aoff[i]];
      bfr[i] = *(const bf16x8*)&Bs[cur * 4096 + boff[i]];
    }
#pragma unroll
    for (int mi = 0; mi < 4; ++mi)
#pragma unroll
      for (int ni = 0; ni < 4; ++ni)
        acc[mi][ni] = __builtin_amdgcn_mfma_f32_16x16x32_bf16(af[mi], bfr[ni],
                                                              acc[mi][ni], 0, 0, 0);
  }
}

// ---------------- output projection (fp32 out), XCD-swizzled --------------
__global__ __launch_bounds__(256) void proj_out_kernel(
    const __bf16* __restrict__ Ob, const __bf16* __restrict__ wob,
    const float* __restrict__ bo, float* __restrict__ out) {
  __shared__ __align__(16) __bf16 As[2 * 128 * 32];
  __shared__ __align__(16) __bf16 Bs[2 * 128 * 32];
  // swizzle: same m-panel -> same XCD (L&7 = mp&7); per-XCD set = 8 A-panels
  // + 8 B-panels = 4 MB = one L2.
  const int lid = blockIdx.x;
  const int xcd = lid & 7, slot = lid >> 3;      // slot 0..63
  const int mp = xcd + 8 * (slot >> 3);          // 0..63
  const int np = slot & 7;                       // 0..7
  const int m0 = mp * 128, n0 = np * 128;
  floatx4 acc[4][4] = {};
  gemm_db128(Ob + (size_t)m0 * HH, wob + (size_t)n0 * HH, As, Bs, acc);
  const int t = threadIdx.x, lane = t & 63, quad = lane >> 4, l16 = lane & 15;
  const int wid = t >> 6, wm = (wid >> 1) * 64, wn = (wid & 1) * 64;
#pragma unroll
  for (int ni = 0; ni < 4; ++ni) {
    int n = n0 + wn + ni * 16 + l16;
    float bval = bo[n];
#pragma unroll
    for (int mi = 0; mi < 4; ++mi)
#pragma unroll
      for (int r = 0; r < 4; ++r) {
        int m = m0 + wm + mi * 16 + quad * 4 + r;
        out[(size_t)m * HH + n] = acc[mi][ni][r] + bval;
      }
  }
}

// ---------------- flash attention, shift-free softmax, XCD-swizzled -------
// flat grid 512: L = qt*64 + bh  =>  L&7 = bh&7 -> all 8 q-blocks of one
// (b,h) share an XCD; that (b,h)'s K/V (1MB) stays hot in its L2.
// R8: P transpose done in-register: per (hf,mq) pack p into 4 dwords
// c[m][j] = pk(p[m][2j],p[m][2j+1]) (lane quad holds k' = m*16+quad*4+r),
// then 2x v_permlane16_swap_b32 -> dwords [X0,X1,Y0,Y1] form an A-frag
// whose quad->k-chunk map is sigma=(0,2,1,3); V reads use the same sigma.
__global__ __launch_bounds__(256, 2) void attn_kernel(
    const __bf16* __restrict__ Q, const __bf16* __restrict__ Kc,
    const __bf16* __restrict__ Vt, __bf16* __restrict__ Ob) {
  __shared__ __align__(16) __bf16 Ks[2][64 * 64];
  __shared__ __align__(16) __bf16 Vs[2][64 * 64];

  const int t = threadIdx.x, lane = t & 63, quad = lane >> 4, l16 = lane & 15;
  const int wid = t >> 6;
  const int L = blockIdx.x;
  const int qt = L >> 6, bhx = L & 63;
  const int b = bhx >> 4, h = bhx & 15;
  const size_t bh = (size_t)b * NHH + h;
  const __bf16* Qg = Q + (bh * SS + (size_t)qt * 256) * DD;
  const __bf16* Kg = Kc + bh * SS * DD;
  const __bf16* Vg = Vt + bh * DD * SS;

  const int srow = t >> 3;  // 0..31
  const int sc = t & 7;

  const __bf16* KgA = Kg + (size_t)srow * DD + (sc ^ swz3(srow)) * 8;
  const __bf16* KgB = Kg + (size_t)(srow + 32) * DD + (sc ^ swz3(srow + 32)) * 8;
  const __bf16* VgA = Vg + (size_t)srow * SS + (sc ^ swz3(srow)) * 8;
  const __bf16* VgB = Vg + (size_t)(srow + 32) * SS + (sc ^ swz3(srow + 32)) * 8;

  bf16x8 qf[4][2];
#pragma unroll
  for (int ni = 0; ni < 4; ++ni)
#pragma unroll
    for (int ks = 0; ks < 2; ++ks)
      qf[ni][ks] = *(const bf16x8*)(Qg + (size_t)(wid * 64 + ni * 16 + l16) * DD
                                    + (ks * 4 + quad) * 8);

  floatx4 oacc[4][4] = {};
  float rsum[4] = {0.f, 0.f, 0.f, 0.f};

  // K-frag offsets (QK^T): natural chunk order.
  int koff[4][2];
#pragma unroll
  for (int mi = 0; mi < 4; ++mi) {
    int r = mi * 16 + l16;
#pragma unroll
    for (int ks = 0; ks < 2; ++ks)
      koff[mi][ks] = r * 64 + ((ks * 4 + quad) ^ swz3(r)) * 8;
  }
  // V-frag offsets (PV): sigma-permuted chunk order (0,2,1,3) to match the
  // permlane-built A-fragment.
  const int sq = ((quad & 1) << 1) | (quad >> 1);  // 0->0 1->2 2->1 3->3
  int voff[4][2];
#pragma unroll
  for (int nj = 0; nj < 4; ++nj) {
    int r = nj * 16 + l16;
#pragma unroll
    for (int hf = 0; hf < 2; ++hf)
      voff[nj][hf] = r * 64 + ((hf * 4 + sq) ^ swz3(r)) * 8;
  }

  async16(KgA, &Ks[0][t * 8]);
  async16(KgB, &Ks[0][2048 + t * 8]);
  async16(VgA, &Vs[0][t * 8]);
  async16(VgB, &Vs[0][2048 + t * 8]);

  for (int kt = 0; kt < SS / 64; ++kt) {
    const int cur = kt & 1;
    __syncthreads();

    if (kt + 1 < SS / 64) {
      const int kk = (kt + 1) * 64;
      const int nxt = cur ^ 1;
      async16(KgA + (size_t)kk * DD, &Ks[nxt][t * 8]);
      async16(KgB + (size_t)kk * DD, &Ks[nxt][2048 + t * 8]);
      async16(VgA + kk, &Vs[nxt][t * 8]);
      async16(VgB + kk, &Vs[nxt][2048 + t * 8]);
    }

    // S^T = K Q^T : sacc[mi][ni] holds S^T[k = mi*16+quad*4+r][q = ni*16+l16]
    floatx4 sacc[4][4];
#pragma unroll
    for (int mi = 0; mi < 4; ++mi)
#pragma unroll
      for (int ni = 0; ni < 4; ++ni) sacc[mi][ni] = floatx4{0.f, 0.f, 0.f, 0.f};
#pragma unroll
    for (int ks = 0; ks < 2; ++ks) {
      bf16x8 kf[4];
#pragma unroll
      for (int mi = 0; mi < 4; ++mi) kf[mi] = *(const bf16x8*)&Ks[cur][koff[mi][ks]];
#pragma unroll
      for (int mi = 0; mi < 4; ++mi)
#pragma unroll
        for (int ni = 0; ni < 4; ++ni)
          sacc[mi][ni] = __builtin_amdgcn_mfma_f32_16x16x32_bf16(kf[mi], qf[ni][ks],
                                                                 sacc[mi][ni], 0, 0, 0);
    }

    // p = exp2(s); build PV A-frags in-register (no LDS round trip).
#pragma unroll
    for (int hf = 0; hf < 2; ++hf) {
      bf16x8 ap[4], bv8[4];
#pragma unroll
      for (int mq = 0; mq < 4; ++mq) {
        float p[2][4];
#pragma unroll
        for (int m = 0; m < 2; ++m)
#pragma unroll
          for (int r = 0; r < 4; ++r) {
            float e = __builtin_amdgcn_exp2f(sacc[hf * 2 + m][mq][r]);
            rsum[mq] += e;
            p[m][r] = e;
          }
        unsigned x0 = pkbf16(p[0][0], p[0][1]);  // c[0][0]: k'=quad*4+{0,1}
        unsigned x1 = pkbf16(p[0][2], p[0][3]);  // c[0][1]: k'=quad*4+{2,3}
        unsigned y0 = pkbf16(p[1][0], p[1][1]);  // c[1][0]: k'=16+quad*4+{0,1}
        unsigned y1 = pkbf16(p[1][2], p[1][3]);  // c[1][1]: k'=16+quad*4+{2,3}
        pswap16(x0, y0);  // x0 -> elems{0,1}, y0 -> elems{4,5}
        pswap16(x1, y1);  // x1 -> elems{2,3}, y1 -> elems{6,7}
        uintx4 u = {x0, x1, y0, y1};
        ap[mq] = __builtin_bit_cast(bf16x8, u);
      }
#pragma unroll
      for (int nj = 0; nj < 4; ++nj) bv8[nj] = *(const bf16x8*)&Vs[cur][voff[nj][hf]];
#pragma unroll
      for (int mq = 0; mq < 4; ++mq)
#pragma unroll
        for (int nj = 0; nj < 4; ++nj)
          oacc[mq][nj] = __builtin_amdgcn_mfma_f32_16x16x32_bf16(ap[mq], bv8[nj],
                                                                 oacc[mq][nj], 0, 0, 0);
    }
  }

#pragma unroll
  for (int ni = 0; ni < 4; ++ni) {
    rsum[ni] += __shfl_xor(rsum[ni], 16, 64);
    rsum[ni] += __shfl_xor(rsum[ni], 32, 64);
  }

  const int s0 = qt * 256 + wid * 64;
#pragma unroll
  for (int mq = 0; mq < 4; ++mq) {
#pragma unroll
    for (int r = 0; r < 4; ++r) {
      float inv = 1.f / __shfl(rsum[mq], quad * 4 + r, 64);
      int s = s0 + mq * 16 + quad * 4 + r;
#pragma unroll
      for (int nj = 0; nj < 4; ++nj) {
        int d = nj * 16 + l16;
        Ob[((size_t)b * SS + s) * HH + h * DD + d] = (__bf16)(oacc[mq][nj][r] * inv);
      }
    }
  }
}

extern "C" void kernel_launch(void* const* d_in, const int* in_sizes, int n_in,
                              void* d_out, int out_size, void* d_ws, size_t ws_size,
                              hipStream_t stream) {
  const float* x  = (const float*)d_in[0];
  const float* Wq = (const float*)d_in[1];
  const float* bq = (const float*)d_in[2];
  const float* Wk = (const float*)d_in[3];
  const float* bk = (const float*)d_in[4];
  const float* Wv = (const float*)d_in[5];
  const float* bv = (const float*)d_in[6];
  const float* Wo = (const float*)d_in[7];
  const float* bo = (const float*)d_in[8];
  float* out = (float*)d_out;

  char* ws = (char*)d_ws;
  __bf16* xb  = (__bf16*)(ws);
  __bf16* wqb = (__bf16*)(ws + 16777216);
  __bf16* wkb = (__bf16*)(ws + 18874368);
  __bf16* wvb = (__bf16*)(ws + 20971520);
  __bf16* wob = (__bf16*)(ws + 23068672);
  __bf16* Qb  = (__bf16*)(ws + 25165824);
  __bf16* Kb  = (__bf16*)(ws + 41943040);
  __bf16* Vtb = (__bf16*)(ws + 58720256);
  __bf16* Ob  = (__bf16*)(ws + 75497472);

  cast_bf16_kernel<<<dim3(256, 1, 5), 256, 0, stream>>>(x, Wq, Wk, Wv, Wo,
                                                        xb, wqb, wkb, wvb, wob);
  proj_qkv_kernel<<<dim3(1024), 256, 0, stream>>>(xb, wqb, wkb, wvb,
                                                  bq, bk, bv, Qb, Kb, Vtb);
  attn_kernel<<<dim3(512), 256, 0, stream>>>(Qb, Kb, Vtb, Ob);
  proj_out_kernel<<<dim3(512), 256, 0, stream>>>(Ob, wob, bo, out);
}

// Round 2
// 268.541 us; speedup vs baseline: 1.0624x; 1.0337x over previous
//
#include <hip/hip_runtime.h>

// MHA forward, bf16 MFMA everywhere. B=4 S=2048 H=1024 NH=16 D=64.
// R9: projection GEMMs rewritten as counted-vmcnt phase schedule (T3+T4+T5):
// BM=128 BN=256 BK=64, 512 thr (8 waves, 64x64/wave), triple-buffered LDS
// (144KB, 1 blk/CU), prefetch distance 2, raw s_barrier + vmcnt(6) (never
// drain mid-loop), setprio around 16-MFMA phases. proj_qkv: one mode per
// block (64m x 12n grid=768); proj_out grid=256. attn (R8 permlane) and
// cast unchanged.

#define DEV __device__ __forceinline__

typedef __bf16 bf16x8 __attribute__((ext_vector_type(8)));
typedef __bf16 bf16x4 __attribute__((ext_vector_type(4)));
typedef __bf16 bf16x2 __attribute__((ext_vector_type(2)));
typedef float floatx4 __attribute__((ext_vector_type(4)));
typedef unsigned int uintx4 __attribute__((ext_vector_type(4)));

constexpr int Bdim = 4, SS = 2048, HH = 1024, NHH = 16, DD = 64;
constexpr int MM = Bdim * SS;  // 8192

DEV void async16(const void* g, void* l) {
  __builtin_amdgcn_global_load_lds(
      (const __attribute__((address_space(1))) unsigned int*)g,
      (__attribute__((address_space(3))) unsigned int*)l, 16, 0, 0);
}

DEV int swz3(int r) { return (r ^ (r >> 3)) & 7; }   // 8-chunk rows (64 cols)

// pack two f32 -> one dword of 2 bf16 (compiler emits v_cvt_pk_bf16_f32)
DEV unsigned pkbf16(float lo, float hi) {
  bf16x2 t;
  t[0] = (__bf16)lo;
  t[1] = (__bf16)hi;
  return __builtin_bit_cast(unsigned, t);
}

// v_permlane16_swap_b32: a.row{1,3} <-> b.row{0,2} (rows = 16-lane groups).
DEV void pswap16(unsigned& a, unsigned& b) {
  asm("v_permlane16_swap_b32 %0, %1" : "+v"(a), "+v"(b));
}

// ---------------- cast fp32 -> bf16 ----------------
__global__ __launch_bounds__(256) void cast_bf16_kernel(
    const float* __restrict__ x, const float* __restrict__ wq,
    const float* __restrict__ wk, const float* __restrict__ wv,
    const float* __restrict__ wo,
    __bf16* __restrict__ xb, __bf16* __restrict__ wqb, __bf16* __restrict__ wkb,
    __bf16* __restrict__ wvb, __bf16* __restrict__ wob) {
  const float* src; __bf16* dst; int n4;
  switch (blockIdx.z) {
    case 0: src = x;  dst = xb;  n4 = MM * HH / 4; break;
    case 1: src = wq; dst = wqb; n4 = HH * HH / 4; break;
    case 2: src = wk; dst = wkb; n4 = HH * HH / 4; break;
    case 3: src = wv; dst = wvb; n4 = HH * HH / 4; break;
    default: src = wo; dst = wob; n4 = HH * HH / 4; break;
  }
  int stride = gridDim.x * blockDim.x;
  for (int i = blockIdx.x * blockDim.x + threadIdx.x; i < n4; i += stride) {
    float4 v = ((const float4*)src)[i];
    bf16x4 o;
    o[0] = (__bf16)v.x; o[1] = (__bf16)v.y; o[2] = (__bf16)v.z; o[3] = (__bf16)v.w;
    ((bf16x4*)dst)[i] = o;
  }
}

// ---- 128x256 GEMM core, K=1024, 2-phase/K-tile, counted vmcnt, 3-buf ----
// LDS tiles: A[128][64], B[256][64], row = 8 chunks of 16B, chunk ^= swz3(row).
// Per K-tile(64): stage = 2 A-rounds + 4 B-rounds of 8KB (async16 x6/thread).
// Phases: kk=0/1, each {8x ds_read_b128; 3x async16(tile kt+2); bar;
// lgkmcnt(0); 16 MFMA (setprio); bar}. End of K-tile: vmcnt(6) (tile kt+2's
// 6 loads stay in flight), never 0 until the tail.
DEV void gemm8p(const __bf16* __restrict__ Ablk, const __bf16* __restrict__ Bblk,
                __bf16* Ab, __bf16* Bb, floatx4 acc[4][4]) {
  const int t = threadIdx.x;
  const int lane = t & 63, quad = lane >> 4, l16 = lane & 15;
  const int wid = t >> 6;
  const int wm = (wid >> 2) * 64, wn = (wid & 3) * 64;

  const int rl = t >> 3, ch = t & 7;
  const __bf16* Ag[2];
  Ag[0] = Ablk + (size_t)rl * HH + (ch ^ swz3(rl)) * 8;
  Ag[1] = Ablk + (size_t)(rl + 64) * HH + (ch ^ swz3(rl + 64)) * 8;
  const __bf16* Bg[4];
#pragma unroll
  for (int br = 0; br < 4; ++br)
    Bg[br] = Bblk + (size_t)(rl + 64 * br) * HH + (ch ^ swz3(rl + 64 * br)) * 8;

  int aoff[2][4], boff[2][4];
#pragma unroll
  for (int kk = 0; kk < 2; ++kk)
#pragma unroll
    for (int i = 0; i < 4; ++i) {
      int ra = wm + i * 16 + l16;
      aoff[kk][i] = ra * 64 + (((kk * 4 + quad) ^ swz3(ra)) * 8);
      int rb = wn + i * 16 + l16;
      boff[kk][i] = rb * 64 + (((kk * 4 + quad) ^ swz3(rb)) * 8);
    }

  // prologue: stage K-tiles 0 and 1 (12 loads); wait for tile 0 only.
#pragma unroll
  for (int tile = 0; tile < 2; ++tile) {
    async16(Ag[0] + tile * 64, Ab + tile * 8192 + t * 8);
    async16(Ag[1] + tile * 64, Ab + tile * 8192 + 4096 + t * 8);
#pragma unroll
    for (int br = 0; br < 4; ++br)
      async16(Bg[br] + tile * 64, Bb + tile * 16384 + br * 4096 + t * 8);
  }
  asm volatile("s_waitcnt vmcnt(6)" ::: "memory");
  __builtin_amdgcn_s_barrier();

  int cb = 0, sb = 2;
#pragma unroll 1
  for (int kt = 0; kt < 16; ++kt) {
    const __bf16* Ac = Ab + cb * 8192;
    const __bf16* Bc = Bb + cb * 16384;
    __bf16* Asg = Ab + sb * 8192;
    __bf16* Bsg = Bb + sb * 16384;
    const int ks = (kt + 2) * 64;
    const bool st = kt < 14;

    bf16x8 af[4], bfr[4];
    // ---------------- phase 0 (kk = 0) ----------------
#pragma unroll
    for (int i = 0; i < 4; ++i) af[i] = *(const bf16x8*)&Ac[aoff[0][i]];
#pragma unroll
    for (int i = 0; i < 4; ++i) bfr[i] = *(const bf16x8*)&Bc[boff[0][i]];
    if (st) {
      async16(Ag[0] + ks, Asg + t * 8);
      async16(Ag[1] + ks, Asg + 4096 + t * 8);
      async16(Bg[0] + ks, Bsg + t * 8);
    }
    asm volatile("" ::: "memory");
    __builtin_amdgcn_s_barrier();
    asm volatile("s_waitcnt lgkmcnt(0)" ::: "memory");
    __builtin_amdgcn_sched_barrier(0);
    __builtin_amdgcn_s_setprio(1);
#pragma unroll
    for (int mi = 0; mi < 4; ++mi)
#pragma unroll
      for (int ni = 0; ni < 4; ++ni)
        acc[mi][ni] = __builtin_amdgcn_mfma_f32_16x16x32_bf16(af[mi], bfr[ni],
                                                              acc[mi][ni], 0, 0, 0);
    __builtin_amdgcn_s_setprio(0);
    asm volatile("" ::: "memory");
    __builtin_amdgcn_s_barrier();

    // ---------------- phase 1 (kk = 1) ----------------
#pragma unroll
    for (int i = 0; i < 4; ++i) af[i] = *(const bf16x8*)&Ac[aoff[1][i]];
#pragma unroll
    for (int i = 0; i < 4; ++i) bfr[i] = *(const bf16x8*)&Bc[boff[1][i]];
    if (st) {
      async16(Bg[1] + ks, Bsg + 4096 + t * 8);
      async16(Bg[2] + ks, Bsg + 8192 + t * 8);
      async16(Bg[3] + ks, Bsg + 12288 + t * 8);
    }
    asm volatile("" ::: "memory");
    __builtin_amdgcn_s_barrier();
    asm volatile("s_waitcnt lgkmcnt(0)" ::: "memory");
    __builtin_amdgcn_sched_barrier(0);
    __builtin_amdgcn_s_setprio(1);
#pragma unroll
    for (int mi = 0; mi < 4; ++mi)
#pragma unroll
      for (int ni = 0; ni < 4; ++ni)
        acc[mi][ni] = __builtin_amdgcn_mfma_f32_16x16x32_bf16(af[mi], bfr[ni],
                                                              acc[mi][ni], 0, 0, 0);
    __builtin_amdgcn_s_setprio(0);
    // end of K-tile: ensure tile kt+1 landed; keep tile kt+2's 6 in flight.
    if (st) asm volatile("s_waitcnt vmcnt(6)" ::: "memory");
    else    asm volatile("s_waitcnt vmcnt(0)" ::: "memory");
    asm volatile("" ::: "memory");
    __builtin_amdgcn_s_barrier();

    cb = cb == 2 ? 0 : cb + 1;
    sb = sb == 2 ? 0 : sb + 1;
  }
}

// ---------------- QKV projection: one mode per block ----------------
// grid 768 = 8 xcd x 96 slots: mp = xcd + 8*(slot&7) (x panels stay L2-hot
// per XCD across all nt rounds), nt = slot>>3 in 0..11, mode = nt>>2.
__global__ __launch_bounds__(512, 2) void proj_qkv_kernel(
    const __bf16* __restrict__ xb,
    const __bf16* __restrict__ wqb, const __bf16* __restrict__ wkb,
    const __bf16* __restrict__ wvb,
    const float* __restrict__ bq, const float* __restrict__ bk,
    const float* __restrict__ bv,
    __bf16* __restrict__ Q, __bf16* __restrict__ Kc, __bf16* __restrict__ Vt) {
  __shared__ __align__(16) __bf16 Ab[3][128 * 64];
  __shared__ __align__(16) __bf16 Bb[3][256 * 64];

  const int lid = blockIdx.x;
  const int xcd = lid & 7, slot = lid >> 3;   // slot 0..95
  const int mp = xcd + 8 * (slot & 7);        // 0..63
  const int nt = slot >> 3;                   // 0..11
  const int mode = nt >> 2;
  const int n0 = (nt & 3) * 256;
  const int m0 = mp * 128;

  const __bf16* W = mode == 0 ? wqb : mode == 1 ? wkb : wvb;
  const float* bias = mode == 0 ? bq : mode == 1 ? bk : bv;

  floatx4 acc[4][4] = {};
  gemm8p(xb + (size_t)m0 * HH, W + (size_t)n0 * HH, &Ab[0][0], &Bb[0][0], acc);

  const int t = threadIdx.x, lane = t & 63, quad = lane >> 4, l16 = lane & 15;
  const int wid = t >> 6, wm = (wid >> 2) * 64, wn = (wid & 3) * 64;
  const float qscale = 0.125f * 1.44269504088896f;  // 1/sqrt(D) * log2(e)

#pragma unroll
  for (int ni = 0; ni < 4; ++ni) {
    int n = n0 + wn + ni * 16 + l16;   // 0..1023 within mode
    float bval = bias[n];
    int h = n >> 6, d = n & 63;
#pragma unroll
    for (int mi = 0; mi < 4; ++mi) {
      int mbase = m0 + wm + mi * 16 + quad * 4;
      int bb = mbase >> 11, sbase = mbase & (SS - 1);
      size_t bh = (size_t)(bb * NHH + h);
      if (mode == 2) {
        bf16x4 pv;
#pragma unroll
        for (int r = 0; r < 4; ++r) pv[r] = (__bf16)(acc[mi][ni][r] + bval);
        *(bf16x4*)&Vt[(bh * DD + d) * SS + sbase] = pv;
      } else {
#pragma unroll
        for (int r = 0; r < 4; ++r) {
          float v = acc[mi][ni][r] + bval;
          if (mode == 0) Q [(bh * SS + sbase + r) * DD + d] = (__bf16)(v * qscale);
          else           Kc[(bh * SS + sbase + r) * DD + d] = (__bf16)v;
        }
      }
    }
  }
}

// ---------------- output projection (fp32 out) ----------------
// grid 256 = 8 xcd x 32 slots: mp = xcd + 8*(slot&7), np = slot>>3 in 0..3.
__global__ __launch_bounds__(512, 2) void proj_out_kernel(
    const __bf16* __restrict__ Ob, const __bf16* __restrict__ wob,
    const float* __restrict__ bo, float* __restrict__ out) {
  __shared__ __align__(16) __bf16 Ab[3][128 * 64];
  __shared__ __align__(16) __bf16 Bb[3][256 * 64];

  const int lid = blockIdx.x;
  const int xcd = lid & 7, slot = lid >> 3;   // slot 0..31
  const int mp = xcd + 8 * (slot & 7);        // 0..63
  const int np = slot >> 3;                   // 0..3
  const int m0 = mp * 128, n0 = np * 256;

  floatx4 acc[4][4] = {};
  gemm8p(Ob + (size_t)m0 * HH, wob + (size_t)n0 * HH, &Ab[0][0], &Bb[0][0], acc);

  const int t = threadIdx.x, lane = t & 63, quad = lane >> 4, l16 = lane & 15;
  const int wid = t >> 6, wm = (wid >> 2) * 64, wn = (wid & 3) * 64;
#pragma unroll
  for (int ni = 0; ni < 4; ++ni) {
    int n = n0 + wn + ni * 16 + l16;
    float bval = bo[n];
#pragma unroll
    for (int mi = 0; mi < 4; ++mi)
#pragma unroll
      for (int r = 0; r < 4; ++r) {
        int m = m0 + wm + mi * 16 + quad * 4 + r;
        out[(size_t)m * HH + n] = acc[mi][ni][r] + bval;
      }
  }
}

// ---------------- flash attention, shift-free softmax, XCD-swizzled -------
// flat grid 512: L = qt*64 + bh  =>  L&7 = bh&7 -> all 8 q-blocks of one
// (b,h) share an XCD; that (b,h)'s K/V (1MB) stays hot in its L2.
// R8: P transpose in-register: cvt_pk pairs + 2x v_permlane16_swap_b32 give
// an A-frag with k-chunk->quad map sigma=(0,2,1,3); V reads use same sigma.
__global__ __launch_bounds__(256, 2) void attn_kernel(
    const __bf16* __restrict__ Q, const __bf16* __restrict__ Kc,
    const __bf16* __restrict__ Vt, __bf16* __restrict__ Ob) {
  __shared__ __align__(16) __bf16 Ks[2][64 * 64];
  __shared__ __align__(16) __bf16 Vs[2][64 * 64];

  const int t = threadIdx.x, lane = t & 63, quad = lane >> 4, l16 = lane & 15;
  const int wid = t >> 6;
  const int L = blockIdx.x;
  const int qt = L >> 6, bhx = L & 63;
  const int b = bhx >> 4, h = bhx & 15;
  const size_t bh = (size_t)b * NHH + h;
  const __bf16* Qg = Q + (bh * SS + (size_t)qt * 256) * DD;
  const __bf16* Kg = Kc + bh * SS * DD;
  const __bf16* Vg = Vt + bh * DD * SS;

  const int srow = t >> 3;  // 0..31
  const int sc = t & 7;

  const __bf16* KgA = Kg + (size_t)srow * DD + (sc ^ swz3(srow)) * 8;
  const __bf16* KgB = Kg + (size_t)(srow + 32) * DD + (sc ^ swz3(srow + 32)) * 8;
  const __bf16* VgA = Vg + (size_t)srow * SS + (sc ^ swz3(srow)) * 8;
  const __bf16* VgB = Vg + (size_t)(srow + 32) * SS + (sc ^ swz3(srow + 32)) * 8;

  bf16x8 qf[4][2];
#pragma unroll
  for (int ni = 0; ni < 4; ++ni)
#pragma unroll
    for (int ks = 0; ks < 2; ++ks)
      qf[ni][ks] = *(const bf16x8*)(Qg + (size_t)(wid * 64 + ni * 16 + l16) * DD
                                    + (ks * 4 + quad) * 8);

  floatx4 oacc[4][4] = {};
  float rsum[4] = {0.f, 0.f, 0.f, 0.f};

  int koff[4][2];
#pragma unroll
  for (int mi = 0; mi < 4; ++mi) {
    int r = mi * 16 + l16;
#pragma unroll
    for (int ks = 0; ks < 2; ++ks)
      koff[mi][ks] = r * 64 + ((ks * 4 + quad) ^ swz3(r)) * 8;
  }
  const int sq = ((quad & 1) << 1) | (quad >> 1);  // 0->0 1->2 2->1 3->3
  int voff[4][2];
#pragma unroll
  for (int nj = 0; nj < 4; ++nj) {
    int r = nj * 16 + l16;
#pragma unroll
    for (int hf = 0; hf < 2; ++hf)
      voff[nj][hf] = r * 64 + ((hf * 4 + sq) ^ swz3(r)) * 8;
  }

  async16(KgA, &Ks[0][t * 8]);
  async16(KgB, &Ks[0][2048 + t * 8]);
  async16(VgA, &Vs[0][t * 8]);
  async16(VgB, &Vs[0][2048 + t * 8]);

  for (int kt = 0; kt < SS / 64; ++kt) {
    const int cur = kt & 1;
    __syncthreads();

    if (kt + 1 < SS / 64) {
      const int kk = (kt + 1) * 64;
      const int nxt = cur ^ 1;
      async16(KgA + (size_t)kk * DD, &Ks[nxt][t * 8]);
      async16(KgB + (size_t)kk * DD, &Ks[nxt][2048 + t * 8]);
      async16(VgA + kk, &Vs[nxt][t * 8]);
      async16(VgB + kk, &Vs[nxt][2048 + t * 8]);
    }

    // S^T = K Q^T
    floatx4 sacc[4][4];
#pragma unroll
    for (int mi = 0; mi < 4; ++mi)
#pragma unroll
      for (int ni = 0; ni < 4; ++ni) sacc[mi][ni] = floatx4{0.f, 0.f, 0.f, 0.f};
#pragma unroll
    for (int ks = 0; ks < 2; ++ks) {
      bf16x8 kf[4];
#pragma unroll
      for (int mi = 0; mi < 4; ++mi) kf[mi] = *(const bf16x8*)&Ks[cur][koff[mi][ks]];
#pragma unroll
      for (int mi = 0; mi < 4; ++mi)
#pragma unroll
        for (int ni = 0; ni < 4; ++ni)
          sacc[mi][ni] = __builtin_amdgcn_mfma_f32_16x16x32_bf16(kf[mi], qf[ni][ks],
                                                                 sacc[mi][ni], 0, 0, 0);
    }

    // p = exp2(s); build PV A-frags in-register (no LDS round trip).
#pragma unroll
    for (int hf = 0; hf < 2; ++hf) {
      bf16x8 ap[4], bv8[4];
#pragma unroll
      for (int mq = 0; mq < 4; ++mq) {
        float p[2][4];
#pragma unroll
        for (int m = 0; m < 2; ++m)
#pragma unroll
          for (int r = 0; r < 4; ++r) {
            float e = __builtin_amdgcn_exp2f(sacc[hf * 2 + m][mq][r]);
            rsum[mq] += e;
            p[m][r] = e;
          }
        unsigned x0 = pkbf16(p[0][0], p[0][1]);
        unsigned x1 = pkbf16(p[0][2], p[0][3]);
        unsigned y0 = pkbf16(p[1][0], p[1][1]);
        unsigned y1 = pkbf16(p[1][2], p[1][3]);
        pswap16(x0, y0);
        pswap16(x1, y1);
        uintx4 u = {x0, x1, y0, y1};
        ap[mq] = __builtin_bit_cast(bf16x8, u);
      }
#pragma unroll
      for (int nj = 0; nj < 4; ++nj) bv8[nj] = *(const bf16x8*)&Vs[cur][voff[nj][hf]];
#pragma unroll
      for (int mq = 0; mq < 4; ++mq)
#pragma unroll
        for (int nj = 0; nj < 4; ++nj)
          oacc[mq][nj] = __builtin_amdgcn_mfma_f32_16x16x32_bf16(ap[mq], bv8[nj],
                                                                 oacc[mq][nj], 0, 0, 0);
    }
  }

#pragma unroll
  for (int ni = 0; ni < 4; ++ni) {
    rsum[ni] += __shfl_xor(rsum[ni], 16, 64);
    rsum[ni] += __shfl_xor(rsum[ni], 32, 64);
  }

  const int s0 = qt * 256 + wid * 64;
#pragma unroll
  for (int mq = 0; mq < 4; ++mq) {
#pragma unroll
    for (int r = 0; r < 4; ++r) {
      float inv = 1.f / __shfl(rsum[mq], quad * 4 + r, 64);
      int s = s0 + mq * 16 + quad * 4 + r;
#pragma unroll
      for (int nj = 0; nj < 4; ++nj) {
        int d = nj * 16 + l16;
        Ob[((size_t)b * SS + s) * HH + h * DD + d] = (__bf16)(oacc[mq][nj][r] * inv);
      }
    }
  }
}

extern "C" void kernel_launch(void* const* d_in, const int* in_sizes, int n_in,
                              void* d_out, int out_size, void* d_ws, size_t ws_size,
                              hipStream_t stream) {
  const float* x  = (const float*)d_in[0];
  const float* Wq = (const float*)d_in[1];
  const float* bq = (const float*)d_in[2];
  const float* Wk = (const float*)d_in[3];
  const float* bk = (const float*)d_in[4];
  const float* Wv = (const float*)d_in[5];
  const float* bv = (const float*)d_in[6];
  const float* Wo = (const float*)d_in[7];
  const float* bo = (const float*)d_in[8];
  float* out = (float*)d_out;

  char* ws = (char*)d_ws;
  __bf16* xb  = (__bf16*)(ws);
  __bf16* wqb = (__bf16*)(ws + 16777216);
  __bf16* wkb = (__bf16*)(ws + 18874368);
  __bf16* wvb = (__bf16*)(ws + 20971520);
  __bf16* wob = (__bf16*)(ws + 23068672);
  __bf16* Qb  = (__bf16*)(ws + 25165824);
  __bf16* Kb  = (__bf16*)(ws + 41943040);
  __bf16* Vtb = (__bf16*)(ws + 58720256);
  __bf16* Ob  = (__bf16*)(ws + 75497472);

  cast_bf16_kernel<<<dim3(256, 1, 5), 256, 0, stream>>>(x, Wq, Wk, Wv, Wo,
                                                        xb, wqb, wkb, wvb, wob);
  proj_qkv_kernel<<<dim3(768), 512, 0, stream>>>(xb, wqb, wkb, wvb,
                                                 bq, bk, bv, Qb, Kb, Vtb);
  attn_kernel<<<dim3(512), 256, 0, stream>>>(Qb, Kb, Vtb, Ob);
  proj_out_kernel<<<dim3(256), 512, 0, stream>>>(Ob, wob, bo, out);
}